// Round 14
// baseline (44.831 us; speedup 1.0000x reference)
//
#include <hip/hip_runtime.h>
#include <math.h>

#define EPS_F 1e-8f

__device__ __forceinline__ float frcp(float x) { return __builtin_amdgcn_rcpf(x); }

typedef __fp16 h2f __attribute__((ext_vector_type(2)));

__device__ __forceinline__ unsigned packh2(float x, float y) {
    h2f h = __builtin_amdgcn_cvt_pkrtz(x, y);   // v_cvt_pkrtz_f16_f32
    return __builtin_bit_cast(unsigned, h);
}
__device__ __forceinline__ void unpackh2(unsigned u, float& x, float& y) {
    h2f h = __builtin_bit_cast(h2f, u);
    x = (float)h.x; y = (float)h.y;
}

// (key30 << 32) | payload as a POSITIVE FINITE double (key30 <= 0x3FFFFFFF
// -> bit63=0, exponent field never all-ones -> no NaN/Inf). For positive
// finite doubles IEEE order == bit order -> v_min_f64/v_max_f64 = 2-inst CE
// carrying key + payload together. (Validated round 13: absmax 0.0.)
__device__ __forceinline__ double mkkey(unsigned hi, unsigned lo) {
    unsigned long long u = ((unsigned long long)hi << 32) | (unsigned long long)lo;
    return __builtin_bit_cast(double, u);
}
__device__ __forceinline__ unsigned keypl(double d) {
    return (unsigned)__builtin_bit_cast(unsigned long long, d);
}

__global__ void __launch_bounds__(64) iou3d_init(double* acc) {
    if (threadIdx.x == 0) { acc[0] = 0.0; acc[1] = 0.0; }
}

// ---- per-element candidate construction (reference-exact; rounds 3-13) ----
__device__ __forceinline__ void build(
    int ic,
    const float* __restrict__ pred_boxes, const float* __restrict__ gt_boxes,
    double (&kd)[24], int& onv)
{
    const float* b1 = pred_boxes + (size_t)ic * 7;
    const float* b2 = gt_boxes   + (size_t)ic * 8;

    float x1c = b1[0], y1c = b1[1], w1 = b1[3], h1 = b1[4], a1 = b1[6];
    float w2 = b2[3], h2v = b2[4];
    float s2v = b2[6], c2v = b2[7];
    float tx2 = b2[0] - x1c, ty2 = b2[1] - y1c;   // pred-center-relative frame

    float invn = rsqrtf(s2v * s2v + c2v * c2v);
    float cs2 = c2v * invn, sn2 = s2v * invn;
    const float INV2PI = 0.15915494309189535f;
    float sn1 = __builtin_amdgcn_sinf(a1 * INV2PI);
    float cs1 = __builtin_amdgcn_cosf(a1 * INV2PI);

    const float DX[4] = {0.5f, -0.5f, -0.5f, 0.5f};
    const float DY[4] = {0.5f,  0.5f, -0.5f, -0.5f};
    float c1x[4], c1y[4], c2x[4], c2y[4];
    #pragma unroll
    for (int k = 0; k < 4; ++k) {
        float cx = DX[k] * w1, cy = DY[k] * h1;
        c1x[k] = cx * cs1 - cy * sn1;
        c1y[k] = cx * sn1 + cy * cs1;
        float gx = DX[k] * w2, gy = DY[k] * h2v;
        c2x[k] = gx * cs2 - gy * sn2 + tx2;
        c2y[k] = gx * sn2 + gy * cs2 + ty2;
    }

    float vx[24], vy[24];
    unsigned vmask = 0;
    float sx = 0.f, sy = 0.f;
    const float HB = 0.5f + 1e-6f;   // |p-0.5|<HB  <=>  -1e-6<p<1+1e-6

    {
        float abx = c2x[1] - c2x[0], aby = c2y[1] - c2y[0];
        float adx = c2x[3] - c2x[0], ady = c2y[3] - c2y[0];
        float iab = frcp(abx * abx + aby * aby);
        float iad = frcp(adx * adx + ady * ady);
        #pragma unroll
        for (int k = 0; k < 4; ++k) {
            float amx = c1x[k] - c2x[0], amy = c1y[k] - c2y[0];
            float pab = (abx * amx + aby * amy) * iab;
            float pad = (adx * amx + ady * amy) * iad;
            bool ok = (fabsf(pab - 0.5f) < HB) && (fabsf(pad - 0.5f) < HB);
            vx[k] = c1x[k]; vy[k] = c1y[k];
            vmask |= ok ? (1u << k) : 0u;
            sx += ok ? c1x[k] : 0.f;
            sy += ok ? c1y[k] : 0.f;
        }
        abx = c1x[1] - c1x[0]; aby = c1y[1] - c1y[0];
        adx = c1x[3] - c1x[0]; ady = c1y[3] - c1y[0];
        iab = frcp(abx * abx + aby * aby);
        iad = frcp(adx * adx + ady * ady);
        #pragma unroll
        for (int k = 0; k < 4; ++k) {
            float amx = c2x[k] - c1x[0], amy = c2y[k] - c1y[0];
            float pab = (abx * amx + aby * amy) * iab;
            float pad = (adx * amx + ady * amy) * iad;
            bool ok = (fabsf(pab - 0.5f) < HB) && (fabsf(pad - 0.5f) < HB);
            vx[4 + k] = c2x[k]; vy[4 + k] = c2y[k];
            vmask |= ok ? (1u << (4 + k)) : 0u;
            sx += ok ? c2x[k] : 0.f;
            sy += ok ? c2y[k] : 0.f;
        }
    }

    // 16 edge-pair points — REFERENCE-EXACT formulas (t is the NEGATED
    // standard parameter; replicate, not fix)
    #pragma unroll
    for (int ii = 0; ii < 4; ++ii) {
        float ex1 = c1x[ii],       ey1 = c1y[ii];
        float ex2 = c1x[(ii+1)&3], ey2 = c1y[(ii+1)&3];
        #pragma unroll
        for (int jj = 0; jj < 4; ++jj) {
            float ex3 = c2x[jj],       ey3 = c2y[jj];
            float ex4 = c2x[(jj+1)&3], ey4 = c2y[(jj+1)&3];
            float num  = (ex2-ex1)*(ey3-ey4) - (ey2-ey1)*(ex3-ex4);
            float dent = (ex1-ex3)*(ey3-ey4) - (ey1-ey3)*(ex3-ex4);
            float denu = (ex1-ex3)*(ey1-ey2) - (ey1-ey3)*(ex1-ex2);
            float rn = frcp(num + EPS_F);
            float t = dent * rn;
            float u = -denu * rn;
            bool ok = (fabsf(t - 0.5f) < 0.5f) && (fabsf(u - 0.5f) < 0.5f) &&
                      (num != 0.f);
            int idx = 8 + ii*4 + jj;
            float px_ = ex1 + t * (ex2 - ex1);
            float py_ = ey1 + t * (ey2 - ey1);
            vx[idx] = px_; vy[idx] = py_;
            vmask |= ok ? (1u << idx) : 0u;
            sx += ok ? px_ : 0.f;
            sy += ok ? py_ : 0.f;
        }
    }

    int nv = __popc(vmask);
    float rdn = frcp((float)(nv < 1 ? 1 : nv));
    float mx = sx * rdn, my = sy * rdn;

    // angle pass: pseudo-angle p in [-3,3] (monotone in atan2); p+3 >= 0 so
    // float bits are monotone -> key30 = bits(p+3)>>2 (max 0x10400001 <
    // invalid 0x3FFFFFFF). Payload = CENTROID-RELATIVE f16x2 coords.
    #pragma unroll
    for (int k = 0; k < 24; ++k) {
        float dx = vx[k] - mx, dy = vy[k] - my;
        float dd = fabsf(dx) + fabsf(dy);
        float tt = (dd > 0.f) ? dy * frcp(dd) : 0.f;
        float p  = (dx >= 0.f) ? tt : (copysignf(2.f, dy) - tt);
        unsigned key30 = ((unsigned)__float_as_int(p + 3.0f)) >> 2;
        bool v = (vmask >> k) & 1u;
        kd[k] = mkkey(v ? key30 : 0x3FFFFFFFu, packh2(dx, dy));
    }

    onv = nv;
}

// ---- pair core: build x2, f64-CE interleaved sort + shoelace + epilogue ----
__device__ __forceinline__ void pair_core(
    int icA, int icB, float mA, float mB,
    const float* __restrict__ pred_iou,
    const float* __restrict__ pred_boxes,
    const float* __restrict__ gt_boxes,
    float& wabs, float& mval)
{
    double kdA[24], kdB[24];
    int nvA, nvB;
    build(icA, pred_boxes, gt_boxes, kdA, nvA);
    build(icB, pred_boxes, gt_boxes, kdB, nvB);

    // Batcher odd-even mergesort (32-net pruned to slots <24; validated
    // rounds 3-13). CE = v_min_f64 + v_max_f64, two networks interleaved.
    #pragma unroll
    for (int pb = 1; pb < 32; pb <<= 1) {
      #pragma unroll
      for (int qb = pb; qb >= 1; qb >>= 1) {
        #pragma unroll
        for (int jb = qb % pb; jb + qb < 32; jb += 2 * qb) {
          #pragma unroll
          for (int ib = 0; ib < qb; ++ib) {
            int a = jb + ib, b = jb + ib + qb;
            if (b < 24 && (a / (2 * pb)) == (b / (2 * pb))) {
                double a0 = kdA[a], b0 = kdA[b];
                kdA[a] = fmin(a0, b0);
                kdA[b] = fmax(a0, b0);
                double a1 = kdB[a], b1 = kdB[b];
                kdB[a] = fmin(a1, b1);
                kdB[b] = fmax(a1, b1);
            }
          }
        }
      }
    }

    // shoelace over sorted centroid-relative payload, A/B interleaved;
    // positions >= nv padded with first sorted vertex (reference-exact)
    float fxA, fyA, fxB, fyB;
    unpackh2(keypl(kdA[0]), fxA, fyA);
    unpackh2(keypl(kdB[0]), fxB, fyB);
    float prxA = fxA, pryA = fyA, areaA = 0.f;
    float prxB = fxB, pryB = fyB, areaB = 0.f;
    #pragma unroll
    for (int k = 1; k < 24; ++k) {
        float xA, yA, xB, yB;
        unpackh2(keypl(kdA[k]), xA, yA);
        unpackh2(keypl(kdB[k]), xB, yB);
        bool useA = (k < nvA), useB = (k < nvB);
        float cxA = useA ? xA : fxA;
        float cyA = useA ? yA : fyA;
        float cxB = useB ? xB : fxB;
        float cyB = useB ? yB : fyB;
        areaA += prxA * cyA - pryA * cxA;
        areaB += prxB * cyB - pryB * cxB;
        prxA = cxA; pryA = cyA;
        prxB = cxB; pryB = cyB;
    }

    const float* b1A = pred_boxes + (size_t)icA * 7;
    const float* b2A = gt_boxes   + (size_t)icA * 8;
    const float* b1B = pred_boxes + (size_t)icB * 7;
    const float* b2B = gt_boxes   + (size_t)icB * 8;

    float i2A = fabsf(areaA) * 0.5f;
    float i2B = fabsf(areaB) * 0.5f;
    float zA = fmaxf(fminf(b1A[2] + b1A[5]*0.5f, b2A[2] + b2A[5]*0.5f)
                   - fmaxf(b1A[2] - b1A[5]*0.5f, b2A[2] - b2A[5]*0.5f), 0.f);
    float zB = fmaxf(fminf(b1B[2] + b1B[5]*0.5f, b2B[2] + b2B[5]*0.5f)
                   - fmaxf(b1B[2] - b1B[5]*0.5f, b2B[2] - b2B[5]*0.5f), 0.f);
    float i3A = i2A * zA, i3B = i2B * zB;
    float vsA = b1A[3]*b1A[4]*b1A[5] + b2A[3]*b2A[4]*b2A[5];
    float vsB = b1B[3]*b1B[4]*b1B[5] + b2B[3]*b2B[4]*b2B[5];
    float iouA = i3A / (vsA - i3A);
    float iouB = i3B / (vsB - i3B);
    wabs = fabsf(pred_iou[icA] - (iouA * 2.f - 1.f)) * mA
         + fabsf(pred_iou[icB] - (iouB * 2.f - 1.f)) * mB;
    mval = mA + mB;
}

__device__ __forceinline__ void block_reduce(float wabs, float mval, double* acc) {
    #pragma unroll
    for (int off = 32; off > 0; off >>= 1) {
        wabs += __shfl_xor(wabs, off);
        mval += __shfl_xor(mval, off);
    }
    __shared__ float sw_[4], sm_[4];
    int lane = threadIdx.x & 63;
    int wid  = threadIdx.x >> 6;
    if (lane == 0) { sw_[wid] = wabs; sm_[wid] = mval; }
    __syncthreads();
    if (threadIdx.x == 0) {
        atomicAdd(&acc[0], (double)(sw_[0] + sw_[1] + sw_[2] + sw_[3]));
        atomicAdd(&acc[1], (double)(sm_[0] + sm_[1] + sm_[2] + sm_[3]));
    }
}

__global__ void __launch_bounds__(256, 2) iou3d_main(
    const float* __restrict__ pred_iou,
    const float* __restrict__ pred_boxes,
    const float* __restrict__ gt_boxes,
    const int*   __restrict__ mask,
    double* __restrict__ acc,
    int N)
{
    int tid = blockIdx.x * blockDim.x + threadIdx.x;
    int iA = 2 * tid, iB = 2 * tid + 1;
    int icA = iA < N ? iA : (N - 1);
    int icB = iB < N ? iB : (N - 1);
    float mA = (iA < N) ? (float)mask[icA] : 0.f;
    float mB = (iB < N) ? (float)mask[icB] : 0.f;

    float wabs, mval;
    pair_core(icA, icB, mA, mB, pred_iou, pred_boxes, gt_boxes, wabs, mval);
    block_reduce(wabs, mval, acc);
}

__global__ void __launch_bounds__(64) iou3d_final(const double* __restrict__ acc,
                                                  float* __restrict__ out) {
    if (threadIdx.x == 0 && blockIdx.x == 0) {
        double s  = acc[0];
        double dm = acc[1];
        double denom = dm > 1e-4 ? dm : 1e-4;
        out[0] = (float)(s / denom);   // LOSS_WEIGHT = 1
    }
}

extern "C" void kernel_launch(void* const* d_in, const int* in_sizes, int n_in,
                              void* d_out, int out_size, void* d_ws, size_t ws_size,
                              hipStream_t stream) {
    const float* pred_iou   = (const float*)d_in[0];
    const float* pred_boxes = (const float*)d_in[1];
    const float* gt_boxes   = (const float*)d_in[2];
    const int*   mask       = (const int*)d_in[3];
    float* out = (float*)d_out;
    double* acc = (double*)d_ws;

    int N = in_sizes[0];
    int blocks = (N + 511) / 512;   // 2 elements per thread

    iou3d_init<<<1, 64, 0, stream>>>(acc);
    iou3d_main<<<blocks, 256, 0, stream>>>(pred_iou, pred_boxes, gt_boxes, mask, acc, N);
    iou3d_final<<<1, 64, 0, stream>>>(acc, out);
}